// Round 2
// baseline (1085.259 us; speedup 1.0000x reference)
//
#include <hip/hip_runtime.h>
#include <cmath>

// ---- static problem shape (TwinsBlock: B=32, H=W=56, C=256, heads=8, ws=7) ----
// Global float tensors are FP32 (reference is jnp.float32). Compute in bf16 MFMA,
// LN/softmax/accum/epilogues in fp32. Intermediates qkv/h stored bf16 in ws;
// x1 stored fp32 in d_out (gemm<2> consumes it in-place, same-thread same-element).
typedef __bf16 bf16;
typedef __bf16 bf16x4 __attribute__((ext_vector_type(4)));
typedef __bf16 bf16x8 __attribute__((ext_vector_type(8)));
typedef float floatx4 __attribute__((ext_vector_type(4)));

constexpr int BATCH = 32;
constexpr int NTOK  = 3136;            // 56*56
constexpr int CDIM  = 256;
constexpr int MROWS = BATCH * NTOK;    // 100352
constexpr int HIDD  = 1024;
constexpr float ATTN_SCALE = 0.17677669529663689f;  // 32^-0.5

__device__ __forceinline__ float gelu_exact(float x) {
    return 0.5f * x * (1.0f + erff(x * 0.70710678118654752440f));
}

// ---- dtype-generic vector loads (always produce fp32) ----
__device__ __forceinline__ void load4(const float* p, float* o) {
    float4 a = *reinterpret_cast<const float4*>(p);
    o[0] = a.x; o[1] = a.y; o[2] = a.z; o[3] = a.w;
}
__device__ __forceinline__ void load4(const bf16* p, float* o) {
    bf16x4 v = *reinterpret_cast<const bf16x4*>(p);
#pragma unroll
    for (int j = 0; j < 4; j++) o[j] = (float)v[j];
}
__device__ __forceinline__ void load8(const float* p, float* o) {
    float4 a = *reinterpret_cast<const float4*>(p);
    float4 b = *reinterpret_cast<const float4*>(p + 4);
    o[0] = a.x; o[1] = a.y; o[2] = a.z; o[3] = a.w;
    o[4] = b.x; o[5] = b.y; o[6] = b.z; o[7] = b.w;
}
__device__ __forceinline__ void load8(const bf16* p, float* o) {
    bf16x8 v = *reinterpret_cast<const bf16x8*>(p);
#pragma unroll
    for (int j = 0; j < 8; j++) o[j] = (float)v[j];
}

// ---------------- per-row LayerNorm stats: mean + rstd ----------------
template<typename T>
__global__ __launch_bounds__(256) void ln_stats_kernel(
    const T* __restrict__ X, float2* __restrict__ stats, int K)
{
    int tok  = (blockIdx.x * 256 + threadIdx.x) >> 6;   // one wave per token
    int lane = threadIdx.x & 63;
    const T* row = X + (size_t)tok * K;
    float s = 0.f, ss = 0.f;
    for (int base = 0; base < K; base += 256) {
        float f[4]; load4(row + base + lane * 4, f);
#pragma unroll
        for (int j = 0; j < 4; j++) { s += f[j]; ss += f[j] * f[j]; }
    }
#pragma unroll
    for (int off = 32; off > 0; off >>= 1) {
        s  += __shfl_xor(s,  off, 64);
        ss += __shfl_xor(ss, off, 64);
    }
    if (lane == 0) {
        float invK = 1.0f / (float)K;
        float mean = s * invK;
        float var  = ss * invK - mean * mean;
        if (var < 0.f) var = 0.f;
        stats[tok] = make_float2(mean, rsqrtf(var + 1e-5f));
    }
}

// ---------------- GEMM: out = epilogue( LN(A) @ Bw + bias ) ----------------
// 64x64 tile, BK=64, 4 waves each doing a 32x32 via 2x2 of mfma_f32_16x16x32_bf16.
// EPI: 0 = bias only, 1 = bias+GELU(exact), 2 = bias+residual(fp32)
template<int EPI, typename TA, typename TO>
__global__ __launch_bounds__(256) void gemm_ln_kernel(
    const TA* __restrict__ A, const float* __restrict__ Bw,
    const float* __restrict__ bias,
    const float2* __restrict__ stats,
    const float* __restrict__ lng, const float* __restrict__ lnb,
    const float* __restrict__ resid,
    TO* __restrict__ out,
    int Nsz, int Ksz)
{
    __shared__ bf16 lA[64 * 72];   // [m][k], pitch 72: rows 16B-aligned, 2-way-free banks
    __shared__ bf16 lB[64 * 72];   // [n][k] (transposed on store)
    const int t = threadIdx.x;
    const int lane = t & 63, w = t >> 6;
    const int quad = lane >> 4, l16 = lane & 15;
    const int wm = (w >> 1) * 32, wn = (w & 1) * 32;
    const size_t m0 = (size_t)blockIdx.y * 64;
    const int n0 = blockIdx.x * 64;
    const int rA = t >> 3;           // 0..31
    const int c8 = (t & 7) * 8;      // 0..56

    floatx4 acc[2][2] = {};

    for (int kc = 0; kc < Ksz; kc += 64) {
#pragma unroll
        for (int half = 0; half < 2; half++) {
            int r = rA + half * 32;
            // A row r, LayerNorm applied on the fly in fp32, rounded to bf16 once
            size_t grow = m0 + r;
            float2 st = stats[grow];
            float av[8], gv[8], bv[8];
            load8(A + grow * Ksz + kc + c8, av);
            load8(lng + kc + c8, gv);
            load8(lnb + kc + c8, bv);
            bf16x8 ov;
#pragma unroll
            for (int j = 0; j < 8; j++)
                ov[j] = (bf16)(((av[j] - st.x) * st.y) * gv[j] + bv[j]);
            *reinterpret_cast<bf16x8*>(&lA[r * 72 + c8]) = ov;
            // B k-row r -> transposed [n][k] store (fp32 -> bf16)
            float wv[8];
            load8(Bw + (size_t)(kc + r) * Nsz + n0 + c8, wv);
#pragma unroll
            for (int j = 0; j < 8; j++)
                lB[(c8 + j) * 72 + r] = (bf16)wv[j];
        }
        __syncthreads();
#pragma unroll
        for (int ks = 0; ks < 64; ks += 32) {
            bf16x8 af[2], bfv[2];
#pragma unroll
            for (int mt = 0; mt < 2; mt++)
                af[mt] = *reinterpret_cast<const bf16x8*>(&lA[(wm + mt * 16 + l16) * 72 + ks + quad * 8]);
#pragma unroll
            for (int nt = 0; nt < 2; nt++)
                bfv[nt] = *reinterpret_cast<const bf16x8*>(&lB[(wn + nt * 16 + l16) * 72 + ks + quad * 8]);
#pragma unroll
            for (int mt = 0; mt < 2; mt++)
#pragma unroll
                for (int nt = 0; nt < 2; nt++)
                    acc[mt][nt] = __builtin_amdgcn_mfma_f32_16x16x32_bf16(af[mt], bfv[nt], acc[mt][nt], 0, 0, 0);
        }
        __syncthreads();
    }

#pragma unroll
    for (int mt = 0; mt < 2; mt++) {
#pragma unroll
        for (int nt = 0; nt < 2; nt++) {
            int col = n0 + wn + nt * 16 + l16;
            float bcol = bias[col];
#pragma unroll
            for (int r = 0; r < 4; r++) {
                size_t row = m0 + wm + mt * 16 + quad * 4 + r;   // C/D: row=(lane>>4)*4+reg
                float v = acc[mt][nt][r] + bcol;
                if (EPI == 1) v = gelu_exact(v);
                if (EPI == 2) v += resid[row * Nsz + col];
                out[row * Nsz + col] = (TO)v;
            }
        }
    }
}

// ---------------- windowed attention, one wave = one (batch, window, head) ----------------
// qkv (bf16) layout per token row (768): [q 0:256 | k 256:512 | v 512:768], head slice h*32.
// S = Q K^T is a single MFMA k-step (HD=32): Q/K fragments loaded straight from global.
// Softmax in fp32 C-layout (cols >=49 -> -inf), P and V^T round-trip per-wave LDS.
__global__ __launch_bounds__(256) void attn_kernel(
    const bf16* __restrict__ qkv, const float* __restrict__ X,
    float* __restrict__ x1)
{
    __shared__ bf16 pbuf[4][64 * 72];   // P[i][j], per wave
    __shared__ bf16 vtbuf[4][32 * 72];  // V^T[d][j], per wave
    const int w = threadIdx.x >> 6, lane = threadIdx.x & 63;
    const int quad = lane >> 4, l16 = lane & 15;
    const int blk = blockIdx.x;
    const int hg = blk & 1, p = (blk >> 1) & 63, b = blk >> 7;
    const int h = hg * 4 + w;
    const int py = p >> 3, px = p & 7;
    const size_t gbase = (size_t)b * NTOK + py * 7 * 56 + px * 7;  // token(i) = gbase + (i/7)*56 + i%7
    bf16* P  = pbuf[w];
    bf16* VT = vtbuf[w];

    // zero V^T so padded j>=49 columns contribute 0
    unsigned int* vz = (unsigned int*)VT;
    for (int i = lane; i < 32 * 72 / 2; i += 64) vz[i] = 0u;

    // load V transposed into LDS
    for (int idx = lane; idx < 49 * 4; idx += 64) {
        int tk = idx >> 2, d8 = (idx & 3) * 8;
        size_t g = gbase + (tk / 7) * 56 + (tk % 7);
        bf16x8 vv = *reinterpret_cast<const bf16x8*>(qkv + g * 768 + 512 + h * 32 + d8);
#pragma unroll
        for (int j = 0; j < 8; j++) VT[(d8 + j) * 72 + tk] = vv[j];
    }

    // Q/K fragments direct from global (A: m=lane&15, k=quad*8+j ; B: n=lane&15, k=quad*8+j)
    bf16x8 qf[4], kf[4];
#pragma unroll
    for (int mt = 0; mt < 4; mt++) {
        int i = mt * 16 + l16; if (i > 48) i = 48;   // clamp pad rows -> finite dups
        size_t g = gbase + (i / 7) * 56 + (i % 7);
        qf[mt] = *reinterpret_cast<const bf16x8*>(qkv + g * 768 +       h * 32 + quad * 8);
        kf[mt] = *reinterpret_cast<const bf16x8*>(qkv + g * 768 + 256 + h * 32 + quad * 8);
    }

    floatx4 s[4][4];
#pragma unroll
    for (int mt = 0; mt < 4; mt++)
#pragma unroll
        for (int nt = 0; nt < 4; nt++) {
            floatx4 z = {};
            s[mt][nt] = __builtin_amdgcn_mfma_f32_16x16x32_bf16(qf[mt], kf[nt], z, 0, 0, 0);
        }

    // row-wise softmax (rows = quad*4+r within each mt tile; cols spread over 16 lanes x 4 nt)
#pragma unroll
    for (int mt = 0; mt < 4; mt++) {
#pragma unroll
        for (int r = 0; r < 4; r++) {
            float mx = -1e30f;
#pragma unroll
            for (int nt = 0; nt < 4; nt++) {
                int col = nt * 16 + l16;
                float v = (col < 49) ? s[mt][nt][r] * ATTN_SCALE : -1e30f;
                s[mt][nt][r] = v;
                mx = fmaxf(mx, v);
            }
#pragma unroll
            for (int off = 1; off < 16; off <<= 1) mx = fmaxf(mx, __shfl_xor(mx, off, 64));
            float sum = 0.f;
#pragma unroll
            for (int nt = 0; nt < 4; nt++) {
                float e = __expf(s[mt][nt][r] - mx);
                s[mt][nt][r] = e;
                sum += e;
            }
#pragma unroll
            for (int off = 1; off < 16; off <<= 1) sum += __shfl_xor(sum, off, 64);
            float inv = 1.0f / sum;
            int prow = mt * 16 + quad * 4 + r;
#pragma unroll
            for (int nt = 0; nt < 4; nt++)
                P[prow * 72 + nt * 16 + l16] = (bf16)(s[mt][nt][r] * inv);
        }
    }

    __syncthreads();   // P/VT writes visible before fragment reads

    // O = P @ V  (K=64 -> two k-steps)
    floatx4 o[4][2] = {};
#pragma unroll
    for (int ks = 0; ks < 2; ks++) {
        bf16x8 pf[4], vf[2];
#pragma unroll
        for (int mt = 0; mt < 4; mt++)
            pf[mt] = *reinterpret_cast<const bf16x8*>(&P[(mt * 16 + l16) * 72 + ks * 32 + quad * 8]);
#pragma unroll
        for (int nt = 0; nt < 2; nt++)
            vf[nt] = *reinterpret_cast<const bf16x8*>(&VT[(nt * 16 + l16) * 72 + ks * 32 + quad * 8]);
#pragma unroll
        for (int mt = 0; mt < 4; mt++)
#pragma unroll
            for (int nt = 0; nt < 2; nt++)
                o[mt][nt] = __builtin_amdgcn_mfma_f32_16x16x32_bf16(pf[mt], vf[nt], o[mt][nt], 0, 0, 0);
    }

    // x1 = x + attn_out (un-window on the fly; LSA applies no proj)
#pragma unroll
    for (int mt = 0; mt < 4; mt++) {
#pragma unroll
        for (int r = 0; r < 4; r++) {
            int i = mt * 16 + quad * 4 + r;
            if (i < 49) {
                size_t g = gbase + (i / 7) * 56 + (i % 7);
#pragma unroll
                for (int nt = 0; nt < 2; nt++) {
                    size_t adr = g * CDIM + h * 32 + nt * 16 + l16;
                    x1[adr] = X[adr] + o[mt][nt][r];
                }
            }
        }
    }
}

// ---------------- launcher ----------------
// ws layout: stats1|stats2|stats3 (2.4 MB) | union(qkv bf16 154 MB, h bf16 205.5 MB)
// x1 lives in d_out (fp32); gemm<2> consumes it in-place (same thread, same element).
extern "C" void kernel_launch(void* const* d_in, const int* in_sizes, int n_in,
                              void* d_out, int out_size, void* d_ws, size_t ws_size,
                              hipStream_t stream) {
    const float* x      = (const float*)d_in[0];
    const float* ln1_g  = (const float*)d_in[1];
    const float* ln1_b  = (const float*)d_in[2];
    const float* qkv_w  = (const float*)d_in[3];
    const float* qkv_b  = (const float*)d_in[4];
    const float* ln2_g  = (const float*)d_in[5];
    const float* ln2_b  = (const float*)d_in[6];
    const float* fc1_w  = (const float*)d_in[7];
    const float* fc1_b  = (const float*)d_in[8];
    const float* mlp_g  = (const float*)d_in[9];
    const float* mlp_b  = (const float*)d_in[10];
    const float* fc2_w  = (const float*)d_in[11];
    const float* fc2_b  = (const float*)d_in[12];
    float* out = (float*)d_out;

    char* ws = (char*)d_ws;
    float2* stats1 = (float2*)ws;  ws += (size_t)MROWS * 8;
    float2* stats2 = (float2*)ws;  ws += (size_t)MROWS * 8;
    float2* stats3 = (float2*)ws;  ws += (size_t)MROWS * 8;
    bf16* qkvb = (bf16*)ws;        // union: qkv (154 MB) dead after attn,
    bf16* hbuf = (bf16*)ws;        // h (205.5 MB) written after -> overlap safe
    float* x1  = out;              // x1 materialized in d_out (fp32)

    ln_stats_kernel<float><<<MROWS / 4, 256, 0, stream>>>(x, stats1, CDIM);
    gemm_ln_kernel<0, float, bf16><<<dim3(768 / 64, MROWS / 64), 256, 0, stream>>>(
        x, qkv_w, qkv_b, stats1, ln1_g, ln1_b, nullptr, qkvb, 768, CDIM);
    attn_kernel<<<BATCH * 64 * 2, 256, 0, stream>>>(qkvb, x, x1);
    ln_stats_kernel<float><<<MROWS / 4, 256, 0, stream>>>(x1, stats2, CDIM);
    gemm_ln_kernel<1, float, bf16><<<dim3(HIDD / 64, MROWS / 64), 256, 0, stream>>>(
        x1, fc1_w, fc1_b, stats2, ln2_g, ln2_b, nullptr, hbuf, HIDD, CDIM);
    ln_stats_kernel<bf16><<<MROWS / 4, 256, 0, stream>>>(hbuf, stats3, HIDD);
    gemm_ln_kernel<2, bf16, float><<<dim3(CDIM / 64, MROWS / 64), 256, 0, stream>>>(
        hbuf, fc2_w, fc2_b, stats3, mlp_g, mlp_b, x1, out, CDIM, HIDD);
}

// Round 3
// 818.267 us; speedup vs baseline: 1.3263x; 1.3263x over previous
//
#include <hip/hip_runtime.h>
#include <cmath>

// ---- TwinsBlock: B=32, H=W=56, C=256, heads=8, ws=7. fp32 I/O, bf16 MFMA ----
typedef __bf16 bf16;
typedef __bf16 bf16x4 __attribute__((ext_vector_type(4)));
typedef __bf16 bf16x8 __attribute__((ext_vector_type(8)));
typedef float floatx4 __attribute__((ext_vector_type(4)));

constexpr int BATCH = 32;
constexpr int NTOK  = 3136;            // 56*56
constexpr int CDIM  = 256;
constexpr int MROWS = BATCH * NTOK;    // 100352
constexpr int HIDD  = 1024;
constexpr float ATTN_SCALE = 0.17677669529663689f;  // 32^-0.5

__device__ __forceinline__ float gelu_exact(float x) {
    return 0.5f * x * (1.0f + erff(x * 0.70710678118654752440f));
}

__device__ __forceinline__ void load8(const bf16* p, float* o) {
    bf16x8 v = *reinterpret_cast<const bf16x8*>(p);
#pragma unroll
    for (int j = 0; j < 8; j++) o[j] = (float)v[j];
}

// async global->LDS, 16B per lane, wave-uniform LDS base + lane*16
__device__ __forceinline__ void gload_lds16(const void* g, void* l) {
    __builtin_amdgcn_global_load_lds(
        (const __attribute__((address_space(1))) void*)g,
        (__attribute__((address_space(3))) void*)l, 16, 0, 0);
}

// ---------------- weight convert + transpose: fp32 [K,N] -> bf16 [N,K] ----------------
__global__ __launch_bounds__(256) void wt_kernel(
    const float* __restrict__ Win, bf16* __restrict__ Wt, int Ksz, int Nsz)
{
    int id = blockIdx.x * 256 + threadIdx.x;       // over N*K, write-coalesced
    int n = id / Ksz, k = id % Ksz;
    Wt[id] = (bf16)Win[(size_t)k * Nsz + n];
}

// ---------------- fused LN (stats+apply): fp32 [M,256] -> bf16 [M,256] ----------------
__global__ __launch_bounds__(256) void ln_apply_f32_kernel(
    const float* __restrict__ X, const float* __restrict__ g,
    const float* __restrict__ b, bf16* __restrict__ Y)
{
    int tok  = (blockIdx.x * 256 + threadIdx.x) >> 6;   // one wave per token
    int lane = threadIdx.x & 63;
    const float* row = X + (size_t)tok * CDIM;
    float4 v = *reinterpret_cast<const float4*>(row + lane * 4);
    float s  = v.x + v.y + v.z + v.w;
    float ss = v.x * v.x + v.y * v.y + v.z * v.z + v.w * v.w;
#pragma unroll
    for (int off = 32; off > 0; off >>= 1) {
        s  += __shfl_xor(s,  off, 64);
        ss += __shfl_xor(ss, off, 64);
    }
    float mean = s * (1.0f / CDIM);
    float var  = ss * (1.0f / CDIM) - mean * mean;
    if (var < 0.f) var = 0.f;
    float rstd = rsqrtf(var + 1e-5f);
    float4 gg = *reinterpret_cast<const float4*>(g + lane * 4);
    float4 bb = *reinterpret_cast<const float4*>(b + lane * 4);
    bf16x4 o;
    o[0] = (bf16)((v.x - mean) * rstd * gg.x + bb.x);
    o[1] = (bf16)((v.y - mean) * rstd * gg.y + bb.y);
    o[2] = (bf16)((v.z - mean) * rstd * gg.z + bb.z);
    o[3] = (bf16)((v.w - mean) * rstd * gg.w + bb.w);
    *reinterpret_cast<bf16x4*>(Y + (size_t)tok * CDIM + lane * 4) = o;
}

// ---------------- fused LN in-place: bf16 [M,1024] (row private to wave) ----------------
__global__ __launch_bounds__(256) void ln_inplace_h_kernel(
    bf16* __restrict__ H, const float* __restrict__ g, const float* __restrict__ b)
{
    int tok  = (blockIdx.x * 256 + threadIdx.x) >> 6;
    int lane = threadIdx.x & 63;
    bf16* row = H + (size_t)tok * HIDD;
    float f[16];
    load8(row + lane * 8, f);
    load8(row + 512 + lane * 8, f + 8);
    float s = 0.f, ss = 0.f;
#pragma unroll
    for (int j = 0; j < 16; j++) { s += f[j]; ss += f[j] * f[j]; }
#pragma unroll
    for (int off = 32; off > 0; off >>= 1) {
        s  += __shfl_xor(s,  off, 64);
        ss += __shfl_xor(ss, off, 64);
    }
    float mean = s * (1.0f / HIDD);
    float var  = ss * (1.0f / HIDD) - mean * mean;
    if (var < 0.f) var = 0.f;
    float rstd = rsqrtf(var + 1e-5f);
    bf16x8 o0, o1;
#pragma unroll
    for (int j = 0; j < 8; j++) {
        o0[j] = (bf16)((f[j]     - mean) * rstd * g[lane * 8 + j]       + b[lane * 8 + j]);
        o1[j] = (bf16)((f[j + 8] - mean) * rstd * g[512 + lane * 8 + j] + b[512 + lane * 8 + j]);
    }
    *reinterpret_cast<bf16x8*>(row + lane * 8) = o0;
    *reinterpret_cast<bf16x8*>(row + 512 + lane * 8) = o1;
}

// ---------------- m97-style GEMM: out = epi( A[M,K] @ Bt[N,K]^T + bias ) ----------------
// 128x128 tile, BK=64, 4 waves (2x2), each 64x64 via 4x4 of mfma_f32_16x16x32_bf16.
// Both operands staged via global_load_lds width=16. EPI: 0 bias, 1 bias+GELU, 2 bias+resid.
template<int EPI, typename TO>
__global__ __launch_bounds__(256) void gemm_bt_kernel(
    const bf16* __restrict__ A, const bf16* __restrict__ Bt,
    const float* __restrict__ bias, const float* __restrict__ resid,
    TO* __restrict__ out, int Nsz, int Ksz)
{
    __shared__ bf16 lA[128 * 64];   // [m][k], pitch 64 (global_load_lds needs contiguity)
    __shared__ bf16 lB[128 * 64];   // [n][k]
    const int t = threadIdx.x;
    const int lane = t & 63, w = t >> 6;
    const int quad = lane >> 4, l16 = lane & 15;
    const int wm = (w >> 1) * 64, wn = (w & 1) * 64;
    const size_t m0 = (size_t)blockIdx.y * 128;
    const int n0 = blockIdx.x * 128;
    const int srow = w * 32 + (lane >> 3);   // staging: 8 lanes per 64-elem row
    const int scol = (lane & 7) * 8;

    floatx4 acc[4][4] = {};

    for (int kc = 0; kc < Ksz; kc += 64) {
#pragma unroll
        for (int j = 0; j < 4; j++) {
            gload_lds16(A  + (m0 + srow + j * 8) * Ksz + kc + scol, &lA[(w * 32 + j * 8) * 64]);
            gload_lds16(Bt + (size_t)(n0 + srow + j * 8) * Ksz + kc + scol, &lB[(w * 32 + j * 8) * 64]);
        }
        __syncthreads();
#pragma unroll
        for (int ks = 0; ks < 64; ks += 32) {
            bf16x8 af[4], bfv[4];
#pragma unroll
            for (int i = 0; i < 4; i++) {
                af[i]  = *reinterpret_cast<const bf16x8*>(&lA[(wm + i * 16 + l16) * 64 + ks + quad * 8]);
                bfv[i] = *reinterpret_cast<const bf16x8*>(&lB[(wn + i * 16 + l16) * 64 + ks + quad * 8]);
            }
#pragma unroll
            for (int mi = 0; mi < 4; mi++)
#pragma unroll
                for (int ni = 0; ni < 4; ni++)
                    acc[mi][ni] = __builtin_amdgcn_mfma_f32_16x16x32_bf16(af[mi], bfv[ni], acc[mi][ni], 0, 0, 0);
        }
        __syncthreads();
    }

#pragma unroll
    for (int mi = 0; mi < 4; mi++) {
#pragma unroll
        for (int ni = 0; ni < 4; ni++) {
            int col = n0 + wn + ni * 16 + l16;
            float bcol = bias[col];
#pragma unroll
            for (int r = 0; r < 4; r++) {
                size_t row = m0 + wm + mi * 16 + quad * 4 + r;   // C/D: row=quad*4+reg
                float v = acc[mi][ni][r] + bcol;
                if (EPI == 1) v = gelu_exact(v);
                if (EPI == 2) v += resid[row * Nsz + col];
                out[row * Nsz + col] = (TO)v;
            }
        }
    }
}

// ---------------- windowed attention, one wave = one (batch, window, head) ----------------
__global__ __launch_bounds__(256) void attn_kernel(
    const bf16* __restrict__ qkv, const float* __restrict__ X,
    float* __restrict__ x1)
{
    __shared__ bf16 pbuf[4][64 * 72];   // P[i][j], per wave
    __shared__ bf16 vtbuf[4][32 * 72];  // V^T[d][j], per wave
    const int w = threadIdx.x >> 6, lane = threadIdx.x & 63;
    const int quad = lane >> 4, l16 = lane & 15;
    const int blk = blockIdx.x;
    const int hg = blk & 1, p = (blk >> 1) & 63, b = blk >> 7;
    const int h = hg * 4 + w;
    const int py = p >> 3, px = p & 7;
    const size_t gbase = (size_t)b * NTOK + py * 7 * 56 + px * 7;
    bf16* P  = pbuf[w];
    bf16* VT = vtbuf[w];

    unsigned int* vz = (unsigned int*)VT;
    for (int i = lane; i < 32 * 72 / 2; i += 64) vz[i] = 0u;

    for (int idx = lane; idx < 49 * 4; idx += 64) {
        int tk = idx >> 2, d8 = (idx & 3) * 8;
        size_t g = gbase + (tk / 7) * 56 + (tk % 7);
        bf16x8 vv = *reinterpret_cast<const bf16x8*>(qkv + g * 768 + 512 + h * 32 + d8);
#pragma unroll
        for (int j = 0; j < 8; j++) VT[(d8 + j) * 72 + tk] = vv[j];
    }

    bf16x8 qf[4], kf[4];
#pragma unroll
    for (int mt = 0; mt < 4; mt++) {
        int i = mt * 16 + l16; if (i > 48) i = 48;   // clamp pad rows -> finite dups
        size_t g = gbase + (i / 7) * 56 + (i % 7);
        qf[mt] = *reinterpret_cast<const bf16x8*>(qkv + g * 768 +       h * 32 + quad * 8);
        kf[mt] = *reinterpret_cast<const bf16x8*>(qkv + g * 768 + 256 + h * 32 + quad * 8);
    }

    floatx4 s[4][4];
#pragma unroll
    for (int mt = 0; mt < 4; mt++)
#pragma unroll
        for (int nt = 0; nt < 4; nt++) {
            floatx4 z = {};
            s[mt][nt] = __builtin_amdgcn_mfma_f32_16x16x32_bf16(qf[mt], kf[nt], z, 0, 0, 0);
        }

#pragma unroll
    for (int mt = 0; mt < 4; mt++) {
#pragma unroll
        for (int r = 0; r < 4; r++) {
            float mx = -1e30f;
#pragma unroll
            for (int nt = 0; nt < 4; nt++) {
                int col = nt * 16 + l16;
                float v = (col < 49) ? s[mt][nt][r] * ATTN_SCALE : -1e30f;
                s[mt][nt][r] = v;
                mx = fmaxf(mx, v);
            }
#pragma unroll
            for (int off = 1; off < 16; off <<= 1) mx = fmaxf(mx, __shfl_xor(mx, off, 64));
            float sum = 0.f;
#pragma unroll
            for (int nt = 0; nt < 4; nt++) {
                float e = __expf(s[mt][nt][r] - mx);
                s[mt][nt][r] = e;
                sum += e;
            }
#pragma unroll
            for (int off = 1; off < 16; off <<= 1) sum += __shfl_xor(sum, off, 64);
            float inv = 1.0f / sum;
            int prow = mt * 16 + quad * 4 + r;
#pragma unroll
            for (int nt = 0; nt < 4; nt++)
                P[prow * 72 + nt * 16 + l16] = (bf16)(s[mt][nt][r] * inv);
        }
    }

    __syncthreads();

    floatx4 o[4][2] = {};
#pragma unroll
    for (int ks = 0; ks < 2; ks++) {
        bf16x8 pf[4], vf[2];
#pragma unroll
        for (int mt = 0; mt < 4; mt++)
            pf[mt] = *reinterpret_cast<const bf16x8*>(&P[(mt * 16 + l16) * 72 + ks * 32 + quad * 8]);
#pragma unroll
        for (int nt = 0; nt < 2; nt++)
            vf[nt] = *reinterpret_cast<const bf16x8*>(&VT[(nt * 16 + l16) * 72 + ks * 32 + quad * 8]);
#pragma unroll
        for (int mt = 0; mt < 4; mt++)
#pragma unroll
            for (int nt = 0; nt < 2; nt++)
                o[mt][nt] = __builtin_amdgcn_mfma_f32_16x16x32_bf16(pf[mt], vf[nt], o[mt][nt], 0, 0, 0);
    }

#pragma unroll
    for (int mt = 0; mt < 4; mt++) {
#pragma unroll
        for (int r = 0; r < 4; r++) {
            int i = mt * 16 + quad * 4 + r;
            if (i < 49) {
                size_t g = gbase + (i / 7) * 56 + (i % 7);
#pragma unroll
                for (int nt = 0; nt < 2; nt++) {
                    size_t adr = g * CDIM + h * 32 + nt * 16 + l16;
                    x1[adr] = X[adr] + o[mt][nt][r];
                }
            }
        }
    }
}

// ---------------- launcher ----------------
// ws: qkv_wt(0.4MB) fc1_wt(0.5MB) fc2_wt(0.5MB) | xn/x1n shared (51.4MB) |
//     union(qkvb 154MB, hbuf 205.5MB) -> ~258.4 MB total. x1 lives in d_out (fp32).
extern "C" void kernel_launch(void* const* d_in, const int* in_sizes, int n_in,
                              void* d_out, int out_size, void* d_ws, size_t ws_size,
                              hipStream_t stream) {
    const float* x      = (const float*)d_in[0];
    const float* ln1_g  = (const float*)d_in[1];
    const float* ln1_b  = (const float*)d_in[2];
    const float* qkv_w  = (const float*)d_in[3];
    const float* qkv_b  = (const float*)d_in[4];
    const float* ln2_g  = (const float*)d_in[5];
    const float* ln2_b  = (const float*)d_in[6];
    const float* fc1_w  = (const float*)d_in[7];
    const float* fc1_b  = (const float*)d_in[8];
    const float* mlp_g  = (const float*)d_in[9];
    const float* mlp_b  = (const float*)d_in[10];
    const float* fc2_w  = (const float*)d_in[11];
    const float* fc2_b  = (const float*)d_in[12];
    float* out = (float*)d_out;

    char* ws = (char*)d_ws;
    bf16* qkv_wt = (bf16*)ws;  ws += (size_t)768 * 256 * 2;
    bf16* fc1_wt = (bf16*)ws;  ws += (size_t)1024 * 256 * 2;
    bf16* fc2_wt = (bf16*)ws;  ws += (size_t)256 * 1024 * 2;
    bf16* xn     = (bf16*)ws;  ws += (size_t)MROWS * CDIM * 2;   // reused as x1n
    bf16* qkvb   = (bf16*)ws;                                     // union with hbuf
    bf16* hbuf   = (bf16*)ws;
    float* x1 = out;

    wt_kernel<<<768,  256, 0, stream>>>(qkv_w, qkv_wt, 256, 768);
    wt_kernel<<<1024, 256, 0, stream>>>(fc1_w, fc1_wt, 256, 1024);
    wt_kernel<<<1024, 256, 0, stream>>>(fc2_w, fc2_wt, 1024, 256);

    ln_apply_f32_kernel<<<MROWS / 4, 256, 0, stream>>>(x, ln1_g, ln1_b, xn);
    gemm_bt_kernel<0, bf16><<<dim3(768 / 128, MROWS / 128), 256, 0, stream>>>(
        xn, qkv_wt, qkv_b, nullptr, qkvb, 768, 256);
    attn_kernel<<<BATCH * 64 * 2, 256, 0, stream>>>(qkvb, x, x1);
    ln_apply_f32_kernel<<<MROWS / 4, 256, 0, stream>>>(x1, ln2_g, ln2_b, xn);
    gemm_bt_kernel<1, bf16><<<dim3(HIDD / 128, MROWS / 128), 256, 0, stream>>>(
        xn, fc1_wt, fc1_b, nullptr, hbuf, HIDD, 256);
    ln_inplace_h_kernel<<<MROWS / 4, 256, 0, stream>>>(hbuf, mlp_g, mlp_b);
    gemm_bt_kernel<2, float><<<dim3(CDIM / 128, MROWS / 128), 256, 0, stream>>>(
        hbuf, fc2_wt, fc2_b, x1, out, CDIM, 1024);
}